// Round 2
// baseline (219.711 us; speedup 1.0000x reference)
//
#include <hip/hip_runtime.h>
#include <math.h>

#define B_    1024
#define L_    200
#define DIM_  100
#define NP    128          // padded N (100 -> 128)
#define K_    1024
#define NCH   16           // split-K chunks per GEMM
#define KCH   (K_ / NCH)   // 64 K-rows per chunk
#define BM    32
#define NTILE (B_ / BM)    // 32 M-tiles

// ---------------- Kernel 1: gather + mean-pool (float4 gathers) -------------
// relP[b,d] = (sum_l emb0[items[b,l]][d]) / slen[b]; emb idx 0 = zero row.
// Also zeroes the 2x32 tile counters (harness poisons ws between iterations;
// stream order guarantees this lands before the GEMMs touch them).
__global__ __launch_bounds__(256) void gather_pool_k(
    const float* __restrict__ emb, const int* __restrict__ items,
    const float* __restrict__ slen, float4* __restrict__ relP4,
    int* __restrict__ cnt) {
  const int b = blockIdx.x;
  const int t = threadIdx.x;
  const int s = t >> 5;            // item stream 0..7
  const int c = t & 31;            // float4 col, valid c<25
  if (b == 0 && t < 2 * NTILE) cnt[t] = 0;
  const int* __restrict__ row = items + b * L_;
  float4 acc = make_float4(0.f, 0.f, 0.f, 0.f);
  if (c < 25) {
    #pragma unroll
    for (int j = 0; j < L_ / 8; ++j) {         // 25 items per thread
      const int idx = row[s + 8 * j];
      if (idx > 0) {
        const float4 v = *(const float4*)&emb[(size_t)(idx - 1) * DIM_ + c * 4];
        acc.x += v.x; acc.y += v.y; acc.z += v.z; acc.w += v.w;
      }
    }
  }
  __shared__ float4 sm[8][32];                 // 4 KB
  sm[s][c] = acc;
  __syncthreads();
  if (s < 4) {
    float4 o = sm[s + 4][c];
    sm[s][c].x += o.x; sm[s][c].y += o.y; sm[s][c].z += o.z; sm[s][c].w += o.w;
  }
  __syncthreads();
  if (s < 2) {
    float4 o = sm[s + 2][c];
    sm[s][c].x += o.x; sm[s][c].y += o.y; sm[s][c].z += o.z; sm[s][c].w += o.w;
  }
  __syncthreads();
  if (s == 0) {
    float4 a0 = sm[0][c], a1 = sm[1][c];
    const float inv = 1.f / slen[b];
    float4 r;
    r.x = (a0.x + a1.x) * inv; r.y = (a0.y + a1.y) * inv;
    r.z = (a0.z + a1.z) * inv; r.w = (a0.w + a1.w) * inv;
    relP4[b * 32 + c] = (c < 25) ? r : make_float4(0.f, 0.f, 0.f, 0.f);
  }
}

// ------- Kernel 2/3: split-K GEMM -> partial tiles, last block reduces ------
// A: [1024][1024] row-major, Bm: [1024][NP], Cpart: [NCH][1024][NP].
// Plain float4 partial stores (NO data atomics -- round-1 showed 2M fp32
// device atomics write through to HBM at ~33 MB and run 10x slow).
// Per-block: one __threadfence (release) + one counter atomic. Last block
// per M-tile sums the 16 partial tiles (L3-hot, 256 KB) and either writes
// the reduced matrix (MODE 0) or applies SELU + row L2-norm (MODE 1).
template <int MODE>
__global__ __launch_bounds__(256) void gemm_splitk_k(
    const float* __restrict__ A,
    const float* __restrict__ Bm,
    float* __restrict__ Cpart,          // [NCH][B_][NP]
    float* __restrict__ Cred,           // [B_][NP]   (MODE 0 output)
    int* __restrict__ cnt,              // [NTILE]
    float* __restrict__ out) {          // [B_][DIM_] (MODE 1 output)
  __shared__ float As[BM][KCH];   // 8 KB
  __shared__ float Bs[KCH][NP];   // 32 KB
  const int t  = threadIdx.x;
  const int m0 = blockIdx.x * BM;
  const int k0 = blockIdx.y * KCH;
  const int tc = t & 31;          // col group: cols tc*4 .. tc*4+3
  const int tr = t >> 5;          // 0..7 : rows tr*4 .. tr*4+3

  // stage A chunk: 2048 floats = 512 float4, 2 per thread
  #pragma unroll
  for (int q = 0; q < 2; ++q) {
    const int f = t + q * 256;            // 0..511
    const int r = f >> 4, kk = (f & 15) * 4;
    *(float4*)&As[r][kk] = *(const float4*)&A[(size_t)(m0 + r) * K_ + (k0 + kk)];
  }
  // stage B chunk: 8192 floats = 2048 float4, 8 per thread, coalesced
  #pragma unroll
  for (int q = 0; q < 8; ++q) {
    const int f = t + q * 256;            // 0..2047
    const int r = f >> 5, cc = (f & 31) * 4;
    *(float4*)&Bs[r][cc] = *(const float4*)&Bm[(size_t)(k0 + r) * NP + cc];
  }
  __syncthreads();

  float acc[4][4] = {};
  #pragma unroll
  for (int kk4 = 0; kk4 < KCH; kk4 += 4) {
    float a[4][4], bb[4][4];
    #pragma unroll
    for (int i = 0; i < 4; ++i)      // A frag: 32-lane broadcast (free)
      *(float4*)a[i] = *(const float4*)&As[tr * 4 + i][kk4];
    #pragma unroll
    for (int j = 0; j < 4; ++j)      // B frag: consecutive-lane b128
      *(float4*)bb[j] = *(const float4*)&Bs[kk4 + j][tc * 4];
    #pragma unroll
    for (int j = 0; j < 4; ++j)
      #pragma unroll
      for (int i = 0; i < 4; ++i)
        #pragma unroll
        for (int q = 0; q < 4; ++q)
          acc[i][q] += a[i][j] * bb[j][q];
  }

  // plain partial store (fast path, round-0 proven)
  float* Cc = Cpart + (size_t)blockIdx.y * B_ * NP;
  #pragma unroll
  for (int i = 0; i < 4; ++i)
    *(float4*)&Cc[(size_t)(m0 + tr * 4 + i) * NP + tc * 4] = *(float4*)acc[i];

  // ---- last-block-per-tile reduction (1 fence + 1 atomic per BLOCK) ----
  __threadfence();                       // release my partial tile
  __shared__ int lastFlag;
  if (t == 0) lastFlag = (atomicAdd(&cnt[blockIdx.x], 1) == NCH - 1);
  __syncthreads();
  if (!lastFlag) return;
  __threadfence();                       // acquire: see all 16 partials

  const float scale = 1.0507009873554804934f;
  const float alpha = 1.6732632423543772848f;
  #pragma unroll
  for (int rr = 0; rr < 4; ++rr) {
    const int row = m0 + tr * 4 + rr;    // 8 groups x 4 rows = 32 rows
    float4 x = make_float4(0.f, 0.f, 0.f, 0.f);
    #pragma unroll
    for (int p = 0; p < NCH; ++p) {
      const float4 w = *(const float4*)&Cpart[((size_t)p * B_ + row) * NP + tc * 4];
      x.x += w.x; x.y += w.y; x.z += w.z; x.w += w.w;
    }
    if (MODE == 0) {
      *(float4*)&Cred[(size_t)row * NP + tc * 4] = x;
    } else {
      float4 sv;
      sv.x = (x.x > 0.f) ? scale * x.x : scale * alpha * expm1f(x.x);
      sv.y = (x.y > 0.f) ? scale * x.y : scale * alpha * expm1f(x.y);
      sv.z = (x.z > 0.f) ? scale * x.z : scale * alpha * expm1f(x.z);
      sv.w = (x.w > 0.f) ? scale * x.w : scale * alpha * expm1f(x.w);
      float ss = (tc < 25) ? (sv.x*sv.x + sv.y*sv.y + sv.z*sv.z + sv.w*sv.w) : 0.f;
      #pragma unroll
      for (int off = 16; off > 0; off >>= 1)   // stays within 32-lane row group
        ss += __shfl_xor(ss, off, 64);
      const float inv = 1.f / sqrtf(ss);
      if (tc < 25) {                     // rows are 400 B -> float4 aligned
        float4 o;
        o.x = sv.x * inv; o.y = sv.y * inv; o.z = sv.z * inv; o.w = sv.w * inv;
        *(float4*)&out[(size_t)row * DIM_ + tc * 4] = o;
      }
    }
  }
}

extern "C" void kernel_launch(void* const* d_in, const int* in_sizes, int n_in,
                              void* d_out, int out_size, void* d_ws, size_t ws_size,
                              hipStream_t stream) {
  const float* emb   = (const float*)d_in[0];  // [50000][100]
  const int*   items = (const int*)d_in[1];    // [1024][200]
  const float* A     = (const float*)d_in[2];  // [1024][1024]
  const float* D     = (const float*)d_in[3];  // [1024][1024]
  const float* slen  = (const float*)d_in[4];  // [1024]
  float* out = (float*)d_out;                  // [1024][100]

  char* ws = (char*)d_ws;
  const size_t matB = (size_t)B_ * NP * sizeof(float);    // 512 KB
  float* relP  = (float*)(ws);                            // [1024][128]
  float* tPart = (float*)(ws + 1 * matB);                 // [16][1024][128] 8 MB
  float* tM    = (float*)(ws + 17 * matB);                // [1024][128]
  float* pPart = (float*)(ws + 18 * matB);                // [16][1024][128] 8 MB
  int*   cnt   = (int*)(ws + 34 * matB);                  // [2][32]

  // 1. rel = mean-pool(gather); zero counters
  gather_pool_k<<<B_, 256, 0, stream>>>(emb, items, slen, (float4*)relP, cnt);
  // 2. tM = A @ rel   (split-K partials; last block per tile reduces -> tM)
  gemm_splitk_k<0><<<dim3(NTILE, NCH), 256, 0, stream>>>(
      A, relP, tPart, tM, cnt, out);
  // 3. out = rownorm(selu(D @ tM))  (last block per tile: reduce + epilogue)
  gemm_splitk_k<1><<<dim3(NTILE, NCH), 256, 0, stream>>>(
      D, tM, pPart, tM, cnt + NTILE, out);
}

// Round 3
// 107.628 us; speedup vs baseline: 2.0414x; 2.0414x over previous
//
#include <hip/hip_runtime.h>
#include <math.h>

#define B_    1024
#define L_    200
#define DIM_  100
#define NP    128          // padded N (100 -> 128)
#define K_    1024
#define NCH   8            // split-K chunks per GEMM (halved vs round 0)
#define KCH   (K_ / NCH)   // 128 K-rows per block
#define KS    64           // staged sub-chunk (2 phases per block)
#define BM    32
#define NTILE (B_ / BM)    // 32 M-tiles

// ---------------- Kernel 1: gather + mean-pool (float4 gathers) -------------
// relP[b,d] = (sum_l emb0[items[b,l]][d]) / slen[b]; emb idx 0 = zero row.
// Indices prefetched into registers (breaks idx->gather dep chain, better MLP
// for the latency-bound random row reads).
__global__ __launch_bounds__(256) void gather_pool_k(
    const float* __restrict__ emb, const int* __restrict__ items,
    const float* __restrict__ slen, float4* __restrict__ relP4) {
  const int b = blockIdx.x;
  const int t = threadIdx.x;
  const int s = t >> 5;            // item stream 0..7
  const int c = t & 31;            // float4 col, valid c<25
  const int* __restrict__ row = items + b * L_;
  int idxs[25];
  #pragma unroll
  for (int j = 0; j < 25; ++j) idxs[j] = row[s + 8 * j];   // 25 items/stream
  float4 acc = make_float4(0.f, 0.f, 0.f, 0.f);
  if (c < 25) {
    #pragma unroll
    for (int j = 0; j < 25; ++j) {
      const int idx = idxs[j];
      if (idx > 0) {
        const float4 v = *(const float4*)&emb[(size_t)(idx - 1) * DIM_ + c * 4];
        acc.x += v.x; acc.y += v.y; acc.z += v.z; acc.w += v.w;
      }
    }
  }
  __shared__ float4 sm[8][32];                 // 4 KB
  sm[s][c] = acc;
  __syncthreads();
  if (s < 4) {
    float4 o = sm[s + 4][c];
    sm[s][c].x += o.x; sm[s][c].y += o.y; sm[s][c].z += o.z; sm[s][c].w += o.w;
  }
  __syncthreads();
  if (s < 2) {
    float4 o = sm[s + 2][c];
    sm[s][c].x += o.x; sm[s][c].y += o.y; sm[s][c].z += o.z; sm[s][c].w += o.w;
  }
  __syncthreads();
  if (s == 0) {
    float4 a0 = sm[0][c], a1 = sm[1][c];
    const float inv = 1.f / slen[b];
    float4 r;
    r.x = (a0.x + a1.x) * inv; r.y = (a0.y + a1.y) * inv;
    r.z = (a0.z + a1.z) * inv; r.w = (a0.w + a1.w) * inv;
    relP4[b * 32 + c] = (c < 25) ? r : make_float4(0.f, 0.f, 0.f, 0.f);
  }
}

// ---------------- Kernel 2/4: split-K GEMM -> private partial chunks --------
// A: [1024][1024] row-major, Bm: [1024][NP], Cpart: [NCH][1024][NP].
// Each block owns a 128-row K-chunk, staged as two 64-row phases (LDS 40 KB).
// NO cross-block sync of any kind (rounds 1-2: device atomics / fences cost
// 10x the kernel itself on gfx950 -- per-XCD L2 writeback storms).
__global__ __launch_bounds__(256) void gemm_splitk_k(
    const float* __restrict__ A,
    const float* __restrict__ Bm,
    float* __restrict__ Cpart) {
  __shared__ float As[BM][KS];   // 8 KB
  __shared__ float Bs[KS][NP];   // 32 KB
  const int t  = threadIdx.x;
  const int m0 = blockIdx.x * BM;
  const int tc = t & 31;         // col group: cols tc*4 .. tc*4+3
  const int tr = t >> 5;         // 0..7 : rows tr*4 .. tr*4+3

  float acc[4][4] = {};
  #pragma unroll
  for (int half = 0; half < 2; ++half) {
    const int k0 = blockIdx.y * KCH + half * KS;
    if (half) __syncthreads();           // LDS reuse across phases
    // stage A sub-chunk: 2048 floats = 512 float4, 2 per thread
    #pragma unroll
    for (int q = 0; q < 2; ++q) {
      const int f = t + q * 256;         // 0..511
      const int r = f >> 4, kk = (f & 15) * 4;
      *(float4*)&As[r][kk] = *(const float4*)&A[(size_t)(m0 + r) * K_ + (k0 + kk)];
    }
    // stage B sub-chunk: 8192 floats = 2048 float4, 8 per thread, coalesced
    #pragma unroll
    for (int q = 0; q < 8; ++q) {
      const int f = t + q * 256;         // 0..2047
      const int r = f >> 5, cc = (f & 31) * 4;
      *(float4*)&Bs[r][cc] = *(const float4*)&Bm[(size_t)(k0 + r) * NP + cc];
    }
    __syncthreads();

    #pragma unroll
    for (int kk4 = 0; kk4 < KS; kk4 += 4) {
      float a[4][4], bb[4][4];
      #pragma unroll
      for (int i = 0; i < 4; ++i)        // A frag: 32-lane broadcast (free)
        *(float4*)a[i] = *(const float4*)&As[tr * 4 + i][kk4];
      #pragma unroll
      for (int j = 0; j < 4; ++j)        // B frag: consecutive-lane b128
        *(float4*)bb[j] = *(const float4*)&Bs[kk4 + j][tc * 4];
      #pragma unroll
      for (int j = 0; j < 4; ++j)
        #pragma unroll
        for (int i = 0; i < 4; ++i)
          #pragma unroll
          for (int q = 0; q < 4; ++q)
            acc[i][q] += a[i][j] * bb[j][q];
    }
  }

  float* Cc = Cpart + (size_t)blockIdx.y * B_ * NP;
  #pragma unroll
  for (int i = 0; i < 4; ++i)
    *(float4*)&Cc[(size_t)(m0 + tr * 4 + i) * NP + tc * 4] = *(float4*)acc[i];
}

// ---------------- Kernel 3: reduce 8 partial chunks -> tM -------------------
__global__ __launch_bounds__(256) void reduce_k(
    const float* __restrict__ part, float* __restrict__ outm) {
  const int i4 = blockIdx.x * 256 + threadIdx.x;       // float4 index, 32768
  const float4* p = (const float4*)part;
  float4 v = p[i4];
  #pragma unroll
  for (int c = 1; c < NCH; ++c) {
    float4 w = p[(size_t)c * (B_ * NP / 4) + i4];
    v.x += w.x; v.y += w.y; v.z += w.z; v.w += w.w;
  }
  ((float4*)outm)[i4] = v;
}

// ------ Kernel 5: sum partials (float4) + SELU + row L2-normalize -----------
// 256 thr = 8 rows x 32 float4-cols; 128 blocks. Fully coalesced f4 reads.
__global__ __launch_bounds__(256) void epilogue_k(
    const float* __restrict__ prePart, float* __restrict__ out) {
  const int t  = threadIdx.x;
  const int tr = t >> 5, tc = t & 31;
  const int row = blockIdx.x * 8 + tr;
  float4 x = make_float4(0.f, 0.f, 0.f, 0.f);
  #pragma unroll
  for (int p = 0; p < NCH; ++p) {
    const float4 w = *(const float4*)&prePart[((size_t)p * B_ + row) * NP + tc * 4];
    x.x += w.x; x.y += w.y; x.z += w.z; x.w += w.w;
  }
  const float scale = 1.0507009873554804934f;
  const float alpha = 1.6732632423543772848f;
  float4 sv;
  sv.x = (x.x > 0.f) ? scale * x.x : scale * alpha * expm1f(x.x);
  sv.y = (x.y > 0.f) ? scale * x.y : scale * alpha * expm1f(x.y);
  sv.z = (x.z > 0.f) ? scale * x.z : scale * alpha * expm1f(x.z);
  sv.w = (x.w > 0.f) ? scale * x.w : scale * alpha * expm1f(x.w);
  float ss = (tc < 25) ? (sv.x*sv.x + sv.y*sv.y + sv.z*sv.z + sv.w*sv.w) : 0.f;
  #pragma unroll
  for (int off = 16; off > 0; off >>= 1)   // stays within each 32-lane group
    ss += __shfl_xor(ss, off, 64);
  const float inv = 1.f / sqrtf(ss);
  if (tc < 25) {                           // 400 B rows -> float4 aligned
    float4 o;
    o.x = sv.x * inv; o.y = sv.y * inv; o.z = sv.z * inv; o.w = sv.w * inv;
    *(float4*)&out[(size_t)row * DIM_ + tc * 4] = o;
  }
}

extern "C" void kernel_launch(void* const* d_in, const int* in_sizes, int n_in,
                              void* d_out, int out_size, void* d_ws, size_t ws_size,
                              hipStream_t stream) {
  const float* emb   = (const float*)d_in[0];  // [50000][100]
  const int*   items = (const int*)d_in[1];    // [1024][200]
  const float* A     = (const float*)d_in[2];  // [1024][1024]
  const float* D     = (const float*)d_in[3];  // [1024][1024]
  const float* slen  = (const float*)d_in[4];  // [1024]
  float* out = (float*)d_out;                  // [1024][100]

  char* ws = (char*)d_ws;
  const size_t matB = (size_t)B_ * NP * sizeof(float);    // 512 KB
  float* relP  = (float*)(ws);                            // [1024][128]
  float* tPart = (float*)(ws + 1 * matB);                 // [8][1024][128] 4 MB
  float* tM    = (float*)(ws + 9 * matB);                 // [1024][128]
  float* pPart = (float*)(ws + 10 * matB);                // [8][1024][128] 4 MB

  // 1. rel = mean-pool(gather)
  gather_pool_k<<<B_, 256, 0, stream>>>(emb, items, slen, (float4*)relP);
  // 2. tPart[p] = A_chunk_p @ rel   (reassociated: D@(A@rel))
  gemm_splitk_k<<<dim3(NTILE, NCH), 256, 0, stream>>>(A, relP, tPart);
  // 3. tM = sum_p tPart[p]
  reduce_k<<<B_ * NP / 4 / 256, 256, 0, stream>>>(tPart, tM);
  // 4. pPart[p] = D_chunk_p @ tM
  gemm_splitk_k<<<dim3(NTILE, NCH), 256, 0, stream>>>(D, tM, pPart);
  // 5. out = rownorm(selu(sum_p pPart[p]))
  epilogue_k<<<B_ / 8, 256, 0, stream>>>(pPart, out);
}

// Round 4
// 107.160 us; speedup vs baseline: 2.0503x; 1.0044x over previous
//
#include <hip/hip_runtime.h>
#include <math.h>

#define B_    1024
#define L_    200
#define LH    100          // items per gather half-block
#define DIM_  100
#define NP    128          // padded N (100 -> 128)
#define K_    1024
#define NCH   8            // split-K chunks per GEMM
#define KCH   (K_ / NCH)   // 128 K-rows per block
#define KS    64           // staged sub-chunk (2 phases per block)
#define BM    32
#define NTILE (B_ / BM)    // 32 M-tiles

// ---------------- Kernel 1: gather + mean-pool (float4 gathers) -------------
// Split: block (b, h) pools items [h*100, h*100+100) of row b and writes
// relP2[h][b][:] = partial_sum / slen[b]  (division distributes over halves).
// 2048 blocks = 8/CU -> 32 waves/CU, doubles TLP for the latency-bound
// random 400 B row reads. gemm1 staging sums the two halves.
__global__ __launch_bounds__(256) void gather_pool_k(
    const float* __restrict__ emb, const int* __restrict__ items,
    const float* __restrict__ slen, float4* __restrict__ relP2) {
  const int b = blockIdx.x;
  const int h = blockIdx.y;        // half 0/1
  const int t = threadIdx.x;
  const int s = t >> 5;            // item stream 0..7
  const int c = t & 31;            // float4 col, valid c<25
  const int* __restrict__ row = items + b * L_ + h * LH;
  int idxs[13];
  #pragma unroll
  for (int j = 0; j < 13; ++j) {   // streams 0-3: 13 items, 4-7: 12 (+pad 0)
    const int g = s + 8 * j;
    idxs[j] = (g < LH) ? row[g] : 0;
  }
  float4 acc = make_float4(0.f, 0.f, 0.f, 0.f);
  if (c < 25) {
    #pragma unroll
    for (int j = 0; j < 13; ++j) {
      const int idx = idxs[j];
      if (idx > 0) {               // idx 0 = padding (zero row)
        const float4 v = *(const float4*)&emb[(size_t)(idx - 1) * DIM_ + c * 4];
        acc.x += v.x; acc.y += v.y; acc.z += v.z; acc.w += v.w;
      }
    }
  }
  __shared__ float4 sm[8][32];                 // 4 KB
  sm[s][c] = acc;
  __syncthreads();
  if (s < 4) {
    float4 o = sm[s + 4][c];
    sm[s][c].x += o.x; sm[s][c].y += o.y; sm[s][c].z += o.z; sm[s][c].w += o.w;
  }
  __syncthreads();
  if (s < 2) {
    float4 o = sm[s + 2][c];
    sm[s][c].x += o.x; sm[s][c].y += o.y; sm[s][c].z += o.z; sm[s][c].w += o.w;
  }
  __syncthreads();
  if (s == 0) {
    float4 a0 = sm[0][c], a1 = sm[1][c];
    const float inv = 1.f / slen[b];
    float4 r;
    r.x = (a0.x + a1.x) * inv; r.y = (a0.y + a1.y) * inv;
    r.z = (a0.z + a1.z) * inv; r.w = (a0.w + a1.w) * inv;
    relP2[((size_t)h * B_ + b) * 32 + c] =
        (c < 25) ? r : make_float4(0.f, 0.f, 0.f, 0.f);
  }
}

// ---------------- Kernel 2/4: split-K GEMM -> private partial chunks --------
// A: [1024][1024] row-major, Bm: [NSUM][1024][NP] (summed during staging),
// Cpart: [NCH][1024][NP]. Each block owns a 128-row K-chunk, staged as two
// 64-row phases (LDS 40 KB). NO cross-block sync (rounds 1-2: device atomics
// / fences cost 10x the kernel itself on gfx950 -- per-XCD L2 writebacks).
template <int NSUM>
__global__ __launch_bounds__(256) void gemm_splitk_k(
    const float* __restrict__ A,
    const float* __restrict__ Bm,
    float* __restrict__ Cpart) {
  __shared__ float As[BM][KS];   // 8 KB
  __shared__ float Bs[KS][NP];   // 32 KB
  const int t  = threadIdx.x;
  const int m0 = blockIdx.x * BM;
  const int tc = t & 31;         // col group: cols tc*4 .. tc*4+3
  const int tr = t >> 5;         // 0..7 : rows tr*4 .. tr*4+3

  float acc[4][4] = {};
  #pragma unroll
  for (int half = 0; half < 2; ++half) {
    const int k0 = blockIdx.y * KCH + half * KS;
    if (half) __syncthreads();           // LDS reuse across phases
    // stage A sub-chunk: 2048 floats = 512 float4, 2 per thread
    #pragma unroll
    for (int q = 0; q < 2; ++q) {
      const int f = t + q * 256;         // 0..511
      const int r = f >> 4, kk = (f & 15) * 4;
      *(float4*)&As[r][kk] = *(const float4*)&A[(size_t)(m0 + r) * K_ + (k0 + kk)];
    }
    // stage B sub-chunk (sum NSUM copies): 2048 float4, 8 per thread
    #pragma unroll
    for (int q = 0; q < 8; ++q) {
      const int f = t + q * 256;         // 0..2047
      const int r = f >> 5, cc = (f & 31) * 4;
      float4 v = *(const float4*)&Bm[(size_t)(k0 + r) * NP + cc];
      if (NSUM == 2) {
        const float4 w = *(const float4*)&Bm[(size_t)(B_ + k0 + r) * NP + cc];
        v.x += w.x; v.y += w.y; v.z += w.z; v.w += w.w;
      }
      *(float4*)&Bs[r][cc] = v;
    }
    __syncthreads();

    #pragma unroll
    for (int kk4 = 0; kk4 < KS; kk4 += 4) {
      float a[4][4], bb[4][4];
      #pragma unroll
      for (int i = 0; i < 4; ++i)        // A frag: 32-lane broadcast (free)
        *(float4*)a[i] = *(const float4*)&As[tr * 4 + i][kk4];
      #pragma unroll
      for (int j = 0; j < 4; ++j)        // B frag: consecutive-lane b128
        *(float4*)bb[j] = *(const float4*)&Bs[kk4 + j][tc * 4];
      #pragma unroll
      for (int j = 0; j < 4; ++j)
        #pragma unroll
        for (int i = 0; i < 4; ++i)
          #pragma unroll
          for (int q = 0; q < 4; ++q)
            acc[i][q] += a[i][j] * bb[j][q];
    }
  }

  float* Cc = Cpart + (size_t)blockIdx.y * B_ * NP;
  #pragma unroll
  for (int i = 0; i < 4; ++i)
    *(float4*)&Cc[(size_t)(m0 + tr * 4 + i) * NP + tc * 4] = *(float4*)acc[i];
}

// ---------------- Kernel 3: reduce 8 partial chunks -> tM -------------------
__global__ __launch_bounds__(256) void reduce_k(
    const float* __restrict__ part, float* __restrict__ outm) {
  const int i4 = blockIdx.x * 256 + threadIdx.x;       // float4 index, 32768
  const float4* p = (const float4*)part;
  float4 v = p[i4];
  #pragma unroll
  for (int c = 1; c < NCH; ++c) {
    float4 w = p[(size_t)c * (B_ * NP / 4) + i4];
    v.x += w.x; v.y += w.y; v.z += w.z; v.w += w.w;
  }
  ((float4*)outm)[i4] = v;
}

// ------ Kernel 5: sum partials (float4) + SELU + row L2-normalize -----------
// 256 thr = 8 rows x 32 float4-cols; 128 blocks. Fully coalesced f4 reads.
__global__ __launch_bounds__(256) void epilogue_k(
    const float* __restrict__ prePart, float* __restrict__ out) {
  const int t  = threadIdx.x;
  const int tr = t >> 5, tc = t & 31;
  const int row = blockIdx.x * 8 + tr;
  float4 x = make_float4(0.f, 0.f, 0.f, 0.f);
  #pragma unroll
  for (int p = 0; p < NCH; ++p) {
    const float4 w = *(const float4*)&prePart[((size_t)p * B_ + row) * NP + tc * 4];
    x.x += w.x; x.y += w.y; x.z += w.z; x.w += w.w;
  }
  const float scale = 1.0507009873554804934f;
  const float alpha = 1.6732632423543772848f;
  float4 sv;
  sv.x = (x.x > 0.f) ? scale * x.x : scale * alpha * expm1f(x.x);
  sv.y = (x.y > 0.f) ? scale * x.y : scale * alpha * expm1f(x.y);
  sv.z = (x.z > 0.f) ? scale * x.z : scale * alpha * expm1f(x.z);
  sv.w = (x.w > 0.f) ? scale * x.w : scale * alpha * expm1f(x.w);
  float ss = (tc < 25) ? (sv.x*sv.x + sv.y*sv.y + sv.z*sv.z + sv.w*sv.w) : 0.f;
  #pragma unroll
  for (int off = 16; off > 0; off >>= 1)   // stays within each 32-lane group
    ss += __shfl_xor(ss, off, 64);
  const float inv = 1.f / sqrtf(ss);
  if (tc < 25) {                           // 400 B rows -> float4 aligned
    float4 o;
    o.x = sv.x * inv; o.y = sv.y * inv; o.z = sv.z * inv; o.w = sv.w * inv;
    *(float4*)&out[(size_t)row * DIM_ + tc * 4] = o;
  }
}

extern "C" void kernel_launch(void* const* d_in, const int* in_sizes, int n_in,
                              void* d_out, int out_size, void* d_ws, size_t ws_size,
                              hipStream_t stream) {
  const float* emb   = (const float*)d_in[0];  // [50000][100]
  const int*   items = (const int*)d_in[1];    // [1024][200]
  const float* A     = (const float*)d_in[2];  // [1024][1024]
  const float* D     = (const float*)d_in[3];  // [1024][1024]
  const float* slen  = (const float*)d_in[4];  // [1024]
  float* out = (float*)d_out;                  // [1024][100]

  char* ws = (char*)d_ws;
  const size_t matB = (size_t)B_ * NP * sizeof(float);    // 512 KB
  float* relP2 = (float*)(ws);                            // [2][1024][128] 1 MB
  float* tPart = (float*)(ws + 2 * matB);                 // [8][1024][128] 4 MB
  float* tM    = (float*)(ws + 10 * matB);                // [1024][128]
  float* pPart = (float*)(ws + 11 * matB);                // [8][1024][128] 4 MB

  // 1. relP2[h] = mean-pool(gather) of item half h  (2 blocks per batch row)
  gather_pool_k<<<dim3(B_, 2), 256, 0, stream>>>(emb, items, slen,
                                                 (float4*)relP2);
  // 2. tPart[p] = A_chunk_p @ (relP2[0]+relP2[1])   (reassociated D@(A@rel))
  gemm_splitk_k<2><<<dim3(NTILE, NCH), 256, 0, stream>>>(A, relP2, tPart);
  // 3. tM = sum_p tPart[p]
  reduce_k<<<B_ * NP / 4 / 256, 256, 0, stream>>>(tPart, tM);
  // 4. pPart[p] = D_chunk_p @ tM
  gemm_splitk_k<1><<<dim3(NTILE, NCH), 256, 0, stream>>>(D, tM, pPart);
  // 5. out = rownorm(selu(sum_p pPart[p]))
  epilogue_k<<<B_ / 8, 256, 0, stream>>>(pPart, out);
}